// Round 6
// baseline (313.720 us; speedup 1.0000x reference)
//
#include <hip/hip_runtime.h>
#include <hip/hip_bf16.h>

#define N_NODES 50000
#define N_EDGES 800000
#define N_REL 8
#define N_BASES 16
#define D 128
#define NCB 196                       // coarse buckets of 256 dsts
#define NSEG (N_NODES * N_REL)        // 400000 (dst,rel) segments
#define NFB 1563                      // fused blocks: ceil(50000/32)

typedef __attribute__((ext_vector_type(8))) short bf16x8;
typedef __attribute__((ext_vector_type(4))) float f32x4;

__device__ inline unsigned short f2bf(float f) {
    unsigned int x = __float_as_uint(f);
    unsigned int r = x + 0x7FFFu + ((x >> 16) & 1u);
    return (unsigned short)(r >> 16);
}
__device__ inline float bf2f(unsigned short u) {
    return __uint_as_float(((unsigned int)u) << 16);
}

// ---------------------------------------------------------------------------
// WbT[r][o][i] = bf16( (r<8 ? sum_b coeff[r,b]*bases[b] : self_loop)[i][o] )
__global__ __launch_bounds__(256) void k_makeW(const float* __restrict__ coeff,
                                               const float* __restrict__ bases,
                                               const float* __restrict__ self_loop,
                                               unsigned short* __restrict__ WbT) {
    const int r = blockIdx.x;  // 0..8
    __shared__ unsigned short tile[128][130];
    if (r < 8) {
        float c[16];
#pragma unroll
        for (int b = 0; b < 16; ++b) c[b] = coeff[r * 16 + b];
        for (int i = threadIdx.x; i < 16384; i += 256) {
            float s = 0.f;
#pragma unroll
            for (int b = 0; b < 16; ++b) s += c[b] * bases[b * 16384 + i];
            tile[i >> 7][i & 127] = f2bf(s);
        }
    } else {
        for (int i = threadIdx.x; i < 16384; i += 256)
            tile[i >> 7][i & 127] = f2bf(self_loop[i]);
    }
    __syncthreads();
    for (int i = threadIdx.x; i < 16384; i += 256) {
        int o = i >> 7, k = i & 127;
        WbT[r * 16384 + o * 128 + k] = tile[k][o];   // [o][k]
    }
}

// ---------------------------------------------------------------------------
// xb = bf16(x)
__global__ __launch_bounds__(256) void k_cvtx(const float* __restrict__ x,
                                              unsigned short* __restrict__ xb) {
    int i = blockIdx.x * 256 + threadIdx.x;   // grid exact: 3125*256 = 800000
    const float4* xp = (const float4*)x;
    float4 a = xp[i * 2], b = xp[i * 2 + 1];
    int4 o;
    o.x = (int)f2bf(a.x) | ((int)f2bf(a.y) << 16);
    o.y = (int)f2bf(a.z) | ((int)f2bf(a.w) << 16);
    o.z = (int)f2bf(b.x) | ((int)f2bf(b.y) << 16);
    o.w = (int)f2bf(b.z) | ((int)f2bf(b.w) << 16);
    ((int4*)xb)[i] = o;
}

// ---------------------------------------------------------------------------
// coarse histogram of dst>>8
__global__ __launch_bounds__(256) void k_histA(const int* __restrict__ ei,
                                               int* __restrict__ ccnt) {
    __shared__ int h[256];
    int t = threadIdx.x;
    h[t] = 0;
    __syncthreads();
    int idx = blockIdx.x * 1024 + t * 4;
    if (idx < N_EDGES) {
        int4 d = *(const int4*)&ei[N_EDGES + idx];
        atomicAdd(&h[d.x >> 8], 1);
        atomicAdd(&h[d.y >> 8], 1);
        atomicAdd(&h[d.z >> 8], 1);
        atomicAdd(&h[d.w >> 8], 1);
    }
    __syncthreads();
    if (t < NCB && h[t]) atomicAdd(&ccnt[t], h[t]);
}

// ---------------------------------------------------------------------------
// exclusive scan of ccnt[196] -> coff[197], gcur; pad roff2 tail with total
__global__ __launch_bounds__(256) void k_scanA1(const int* __restrict__ ccnt,
                                                int* __restrict__ coff,
                                                int* __restrict__ gcur,
                                                int* __restrict__ roff2) {
    int t = threadIdx.x;
    int v = (t < NCB) ? ccnt[t] : 0;
    int lane = t & 63, wv = t >> 6;
    int inc = v;
#pragma unroll
    for (int off = 1; off < 64; off <<= 1) {
        int y = __shfl_up(inc, off);
        if (lane >= off) inc += y;
    }
    __shared__ int ws4[4];
    __shared__ int tot;
    if (lane == 63) ws4[wv] = inc;
    __syncthreads();
    int wb = 0;
    for (int i = 0; i < wv; ++i) wb += ws4[i];
    int ex = wb + inc - v;
    if (t < NCB) { coff[t] = ex; gcur[t] = ex; }
    if (t == NCB - 1) { coff[NCB] = ex + v; tot = ex + v; }
    __syncthreads();
    // pad: segments for dst in [50000, 50016) must be empty
    for (int i = t; i < 192; i += 256) roff2[NSEG + i] = tot;
}

// ---------------------------------------------------------------------------
// bucket edges into coarse segments; rec = src | rel<<16 | (dst&255)<<19
#define ACHUNK 2048
__global__ __launch_bounds__(256) void k_bucketA(const int* __restrict__ ei,
                                                 const int* __restrict__ et,
                                                 int* __restrict__ gcur,
                                                 unsigned int* __restrict__ recA) {
    __shared__ int lcnt[NCB], lbase[NCB];
    const int base = blockIdx.x * ACHUNK;
    const int t = threadIdx.x;
    if (t < NCB) lcnt[t] = 0;
    __syncthreads();
    unsigned int rec[8];
    int mb[8];
#pragma unroll
    for (int i = 0; i < 8; ++i) {
        int e = base + t + i * 256;
        if (e < N_EDGES) {
            int src = ei[e];
            int dst = ei[N_EDGES + e];
            int r = et[e];
            rec[i] = (unsigned)src | ((unsigned)r << 16) | ((unsigned)(dst & 255) << 19);
            mb[i] = dst >> 8;
            atomicAdd(&lcnt[mb[i]], 1);
        } else mb[i] = -1;
    }
    __syncthreads();
    if (t < NCB) lbase[t] = lcnt[t] ? atomicAdd(&gcur[t], lcnt[t]) : 0;
    __syncthreads();
    if (t < NCB) lcnt[t] = 0;
    __syncthreads();
#pragma unroll
    for (int i = 0; i < 8; ++i) {
        if (mb[i] < 0) continue;
        int pos = lbase[mb[i]] + atomicAdd(&lcnt[mb[i]], 1);
        recA[pos] = rec[i];
    }
}

// ---------------------------------------------------------------------------
// per coarse bucket: (dst,rel)-sorted csr16 + roff2 (all LDS atomics)
__global__ __launch_bounds__(256) void k_buildC(const unsigned int* __restrict__ recA,
                                                const int* __restrict__ coff,
                                                int* __restrict__ roff2,
                                                unsigned short* __restrict__ csr16) {
    const int b = blockIdx.x, t = threadIdx.x;
    const int s0 = coff[b], s1 = coff[b + 1];
    __shared__ int h2[2048];    // (dst&255)*8 + rel
    __shared__ int cur2[2048];
    __shared__ int ws4[4];
    for (int i = t; i < 2048; i += 256) h2[i] = 0;
    __syncthreads();
    for (int i = s0 + t; i < s1; i += 256) {
        unsigned int p = recA[i];
        atomicAdd(&h2[((p >> 19) & 255) * 8 + ((p >> 16) & 7)], 1);
    }
    __syncthreads();
    // exclusive scan over 2048 entries, thread t owns [t*8, t*8+8)
    int pre[8], sum = 0;
#pragma unroll
    for (int j = 0; j < 8; ++j) { pre[j] = sum; sum += h2[t * 8 + j]; }
    int lane = t & 63, wv = t >> 6;
    int inc = sum;
#pragma unroll
    for (int off = 1; off < 64; off <<= 1) {
        int y = __shfl_up(inc, off);
        if (lane >= off) inc += y;
    }
    if (lane == 63) ws4[wv] = inc;
    __syncthreads();
    int wb = 0;
    for (int i = 0; i < wv; ++i) wb += ws4[i];
    int ex = wb + inc - sum;
    int dst = (b << 8) + t;
#pragma unroll
    for (int j = 0; j < 8; ++j) cur2[t * 8 + j] = ex + pre[j];
    if (dst < N_NODES) {
#pragma unroll
        for (int j = 0; j < 8; ++j) roff2[dst * 8 + j] = s0 + ex + pre[j];
    }
    __syncthreads();
    for (int i = s0 + t; i < s1; i += 256) {
        unsigned int p = recA[i];
        int idx2 = ((p >> 19) & 255) * 8 + ((p >> 16) & 7);
        int pos = s0 + atomicAdd(&cur2[idx2], 1);
        csr16[pos] = (unsigned short)(p & 0xFFFF);
    }
}

// ---------------------------------------------------------------------------
// FUSED: per block of 32 dsts: aggregate scaled x[src] per (dst,rel) into
// swizzled LDS bf16 tile, then 9-panel MFMA (8 rel + self) -> fp32 out.
__global__ __launch_bounds__(512) void k_fused(const unsigned short* __restrict__ xb,
                                               const unsigned short* __restrict__ WbT,
                                               const unsigned short* __restrict__ csr16,
                                               const int* __restrict__ roff2,
                                               float* __restrict__ out) {
    __shared__ __attribute__((aligned(16))) unsigned char gbb[65536]; // [32 dst][8 rel][128 bf16], swizzled
    __shared__ int roff_s[257];
    const int g = blockIdx.x;
    const int g32 = g * 32;
    const int t = threadIdx.x;
    const int wv = t >> 6, lane = t & 63;

    if (t < 257) roff_s[t] = roff2[g * 256 + t];
    __syncthreads();

    // ---- aggregation: segment s -> dst-local s>>3, rel s&7
    for (int s = wv; s < 256; s += 8) {
        int a0 = roff_s[s];
        int n = roff_s[s + 1] - a0;
        float acc0 = 0.f, acc1 = 0.f;
        for (int j = 0; j < n; ++j) {
            int src = (int)csr16[a0 + j];
            unsigned int v = *(const unsigned int*)&xb[src * D + (lane << 1)];
            acc0 += bf2f((unsigned short)(v & 0xFFFFu));
            acc1 += bf2f((unsigned short)(v >> 16));
        }
        float dinv = 1.0f / fmaxf((float)n, 1.0f);
        unsigned int pk = (unsigned int)f2bf(acc0 * dinv) | ((unsigned int)f2bf(acc1 * dinv) << 16);
        int dl = s >> 3, rel = s & 7;
        *(unsigned int*)&gbb[dl * 2048 + rel * 256 + (((lane << 2)) ^ ((dl & 7) << 4))] = pk;
    }
    __syncthreads();

    // ---- MFMA: wave wv -> cols [wv*16, wv*16+16), rows m*16+...
    const int lr = lane & 15, lg = lane >> 4;
    const int colb = wv << 4;
    f32x4 acc0 = {0.f, 0.f, 0.f, 0.f}, acc1 = {0.f, 0.f, 0.f, 0.f};
    const int swz = (lr & 7) << 4;
#pragma unroll
    for (int rel = 0; rel < 8; ++rel) {
        const unsigned short* Wp = WbT + rel * 16384 + (colb + lr) * 128;
#pragma unroll
        for (int kk = 0; kk < 4; ++kk) {
            int kb = kk * 64 + lg * 16;   // byte offset of the 8-bf16 chunk
            bf16x8 bfr = *(const bf16x8*)&Wp[kk * 32 + lg * 8];
            bf16x8 a0 = *(const bf16x8*)&gbb[lr * 2048 + rel * 256 + (kb ^ swz)];
            bf16x8 a1 = *(const bf16x8*)&gbb[(16 + lr) * 2048 + rel * 256 + (kb ^ swz)];
            acc0 = __builtin_amdgcn_mfma_f32_16x16x32_bf16(a0, bfr, acc0, 0, 0, 0);
            acc1 = __builtin_amdgcn_mfma_f32_16x16x32_bf16(a1, bfr, acc1, 0, 0, 0);
        }
    }
    {   // self-loop panel: A rows straight from xb
        const unsigned short* Wp = WbT + 8 * 16384 + (colb + lr) * 128;
        int r0 = min(g32 + lr, N_NODES - 1);
        int r1 = min(g32 + 16 + lr, N_NODES - 1);
#pragma unroll
        for (int kk = 0; kk < 4; ++kk) {
            bf16x8 bfr = *(const bf16x8*)&Wp[kk * 32 + lg * 8];
            bf16x8 a0 = *(const bf16x8*)&xb[(size_t)r0 * D + kk * 32 + lg * 8];
            bf16x8 a1 = *(const bf16x8*)&xb[(size_t)r1 * D + kk * 32 + lg * 8];
            acc0 = __builtin_amdgcn_mfma_f32_16x16x32_bf16(a0, bfr, acc0, 0, 0, 0);
            acc1 = __builtin_amdgcn_mfma_f32_16x16x32_bf16(a1, bfr, acc1, 0, 0, 0);
        }
    }
#pragma unroll
    for (int q = 0; q < 4; ++q) {
        int row = g32 + lg * 4 + q;
        if (row < N_NODES) out[(size_t)row * D + colb + lr] = acc0[q];
    }
#pragma unroll
    for (int q = 0; q < 4; ++q) {
        int row = g32 + 16 + lg * 4 + q;
        if (row < N_NODES) out[(size_t)row * D + colb + lr] = acc1[q];
    }
}

// ---------------------------------------------------------------------------
extern "C" void kernel_launch(void* const* d_in, const int* in_sizes, int n_in,
                              void* d_out, int out_size, void* d_ws, size_t ws_size,
                              hipStream_t stream) {
    const float* x         = (const float*)d_in[0];
    const float* bases     = (const float*)d_in[1];
    const float* coeff     = (const float*)d_in[2];
    const float* self_loop = (const float*)d_in[3];
    const int*   ei        = (const int*)d_in[4];
    const int*   et        = (const int*)d_in[5];
    float* out = (float*)d_out;

    char* ws = (char*)d_ws;
    size_t o = 0;
    auto alloc = [&](size_t bytes) { size_t r = o; o += (bytes + 255) & ~(size_t)255; return r; };
    size_t o_ccnt   = alloc(256 * 4);                        // zeroed
    size_t zero_end = o;
    size_t o_coff   = alloc((NCB + 1) * 4);
    size_t o_gcur   = alloc(NCB * 4);
    size_t o_recA   = alloc((size_t)N_EDGES * 4);
    size_t o_csr16  = alloc((size_t)N_EDGES * 2);
    size_t o_roff2  = alloc((size_t)(NSEG + 192) * 4);
    size_t o_WbT    = alloc((size_t)9 * 16384 * 2);
    size_t o_xb     = alloc((size_t)N_NODES * D * 2 + 4096);
    if (ws_size < o) return;

    int*            ccnt  = (int*)(ws + o_ccnt);
    int*            coff  = (int*)(ws + o_coff);
    int*            gcur  = (int*)(ws + o_gcur);
    unsigned int*   recA  = (unsigned int*)(ws + o_recA);
    unsigned short* csr16 = (unsigned short*)(ws + o_csr16);
    int*            roff2 = (int*)(ws + o_roff2);
    unsigned short* WbT   = (unsigned short*)(ws + o_WbT);
    unsigned short* xb    = (unsigned short*)(ws + o_xb);

    hipMemsetAsync(ccnt, 0, zero_end, stream);

    k_makeW<<<9, 256, 0, stream>>>(coeff, bases, self_loop, WbT);
    k_cvtx<<<3125, 256, 0, stream>>>(x, xb);
    k_histA<<<(N_EDGES + 1023) / 1024, 256, 0, stream>>>(ei, ccnt);
    k_scanA1<<<1, 256, 0, stream>>>(ccnt, coff, gcur, roff2);
    k_bucketA<<<(N_EDGES + ACHUNK - 1) / ACHUNK, 256, 0, stream>>>(ei, et, gcur, recA);
    k_buildC<<<NCB, 256, 0, stream>>>(recA, coff, roff2, csr16);
    k_fused<<<NFB, 512, 0, stream>>>(xb, WbT, csr16, roff2, out);
}